// Round 1
// baseline (1119.144 us; speedup 1.0000x reference)
//
#include <hip/hip_runtime.h>

#define N_NODES   50000
#define N_EDGES   800000
#define DF        64          // feature dim (D_IN == D_HID == 64)
#define N_GRAPHS  64

// ---------------- degree / norm ----------------

__global__ void k_deg_init(float* __restrict__ deg) {
    int i = blockIdx.x * blockDim.x + threadIdx.x;
    if (i < N_NODES) deg[i] = 1.0f;   // self-loop contributes 1 to every node
}

__global__ void k_deg_count(const int* __restrict__ col, float* __restrict__ deg) {
    int e = blockIdx.x * blockDim.x + threadIdx.x;
    if (e < N_EDGES) atomicAdd(&deg[col[e]], 1.0f);
}

__global__ void k_dinv(float* __restrict__ deg) {
    int i = blockIdx.x * blockDim.x + threadIdx.x;
    if (i < N_NODES) deg[i] = rsqrtf(deg[i]);   // deg >= 1 always (self-loop)
}

// ---------------- GEMM: out = act(in [+ bias]) @ W ----------------
// block = 256 threads, 16 rows per block (50000 % 16 == 0 -> 3125 blocks)
#define ROWS_PER_BLOCK 16

__global__ __launch_bounds__(256)
void k_gemm(const float* __restrict__ in, const float* __restrict__ W,
            const float* __restrict__ bias, float* __restrict__ out,
            int relu_in) {
    __shared__ float Ws[DF][DF];                  // 16 KB
    __shared__ float Xs[ROWS_PER_BLOCK][DF];      // 4 KB

    const int t = threadIdx.x;
    const int row0 = blockIdx.x * ROWS_PER_BLOCK;

    // stage W (4096 floats / 256 threads = 16 each)
    for (int i = t; i < DF * DF; i += 256)
        Ws[i >> 6][i & 63] = W[i];

    // stage X tile, fusing previous layer's bias + ReLU
    for (int i = t; i < ROWS_PER_BLOCK * DF; i += 256) {
        int r = i >> 6, k = i & 63;
        float v = in[(row0 + r) * DF + k];
        if (relu_in) { v += bias[k]; v = v > 0.0f ? v : 0.0f; }
        Xs[r][k] = v;
    }
    __syncthreads();

    const int col   = t & 63;          // wave lane -> output column (stride-1)
    const int rbase = (t >> 6) * 4;    // 4 rows per thread
    float a0 = 0.f, a1 = 0.f, a2 = 0.f, a3 = 0.f;
    #pragma unroll
    for (int k = 0; k < DF; ++k) {
        float w = Ws[k][col];          // 2-way bank alias: free
        a0 += Xs[rbase + 0][k] * w;    // broadcast within wave: free
        a1 += Xs[rbase + 1][k] * w;
        a2 += Xs[rbase + 2][k] * w;
        a3 += Xs[rbase + 3][k] * w;
    }
    out[(row0 + rbase + 0) * DF + col] = a0;
    out[(row0 + rbase + 1) * DF + col] = a1;
    out[(row0 + rbase + 2) * DF + col] = a2;
    out[(row0 + rbase + 3) * DF + col] = a3;
}

// ---------------- agg init with self-loop: agg[i] = h[i] * dinv[n]^2 ----------------
__global__ __launch_bounds__(256)
void k_selfinit(const float* __restrict__ h, const float* __restrict__ dinv,
                float* __restrict__ agg) {
    int i = blockIdx.x * blockDim.x + threadIdx.x;
    if (i < N_NODES * DF) {
        float di = dinv[i >> 6];
        agg[i] = h[i] * di * di;
    }
}

// ---------------- edge scatter: agg[col] += h[row] * dinv[row]*dinv[col] ----------------
// one wave (64 lanes) per edge; lane = feature index
__global__ __launch_bounds__(256)
void k_scatter(const int* __restrict__ row, const int* __restrict__ col,
               const float* __restrict__ dinv, const float* __restrict__ h,
               float* __restrict__ agg) {
    int idx = blockIdx.x * blockDim.x + threadIdx.x;
    int e = idx >> 6;
    int d = idx & 63;
    if (e < N_EDGES) {
        int r = row[e], c = col[e];
        float w = dinv[r] * dinv[c];
        atomicAdd(&agg[c * DF + d], h[r * DF + d] * w);
    }
}

// ---------------- pool: sum relu(agg + b3) per graph + counts ----------------
__global__ __launch_bounds__(256)
void k_pool(const float* __restrict__ agg, const float* __restrict__ b,
            const int* __restrict__ batch, float* __restrict__ pool,
            float* __restrict__ cnt) {
    int idx = blockIdx.x * blockDim.x + threadIdx.x;
    int n = idx >> 6, d = idx & 63;
    if (n < N_NODES) {
        int g = batch[n];
        float v = agg[idx] + b[d];
        v = v > 0.0f ? v : 0.0f;
        atomicAdd(&pool[g * DF + d], v);
        if (d == 0) atomicAdd(&cnt[g], 1.0f);
    }
}

__global__ void k_div(const float* __restrict__ pool, const float* __restrict__ cnt,
                      float* __restrict__ out) {
    int idx = blockIdx.x * blockDim.x + threadIdx.x;
    if (idx < N_GRAPHS * DF) {
        float c = cnt[idx >> 6];
        out[idx] = pool[idx] / fmaxf(c, 1.0f);
    }
}

// ---------------- launch ----------------

extern "C" void kernel_launch(void* const* d_in, const int* in_sizes, int n_in,
                              void* d_out, int out_size, void* d_ws, size_t ws_size,
                              hipStream_t stream) {
    const float* x     = (const float*)d_in[0];
    const int*   ei    = (const int*)d_in[1];      // [2, E] flat: row then col
    const int*   batch = (const int*)d_in[2];
    const float* W1    = (const float*)d_in[3];
    const float* b1    = (const float*)d_in[4];
    const float* W2    = (const float*)d_in[5];
    const float* b2    = (const float*)d_in[6];
    const float* W3    = (const float*)d_in[7];
    const float* b3    = (const float*)d_in[8];
    float* out = (float*)d_out;

    const int* row = ei;             // source
    const int* col = ei + N_EDGES;   // target (aggregation index)

    // workspace layout (floats)
    float* ws   = (float*)d_ws;
    float* dinv = ws;                         // 50000 (rounded to 50176)
    float* bufA = ws + 50176;                 // 50000*64 = 3,200,000
    float* bufB = bufA + N_NODES * DF;        // 3,200,000
    float* pool = bufB + N_NODES * DF;        // 64*64
    float* cnt  = pool + N_GRAPHS * DF;       // 64

    const int nblk_N   = (N_NODES + 255) / 256;        // 196
    const int nblk_E   = (N_EDGES + 255) / 256;        // 3125
    const int nblk_ND  = (N_NODES * DF) / 256;         // 12500
    const int nblk_ED  = (N_EDGES * DF) / 256;         // 200000
    const int nblk_G   = 3125;                         // 50000/16

    // degree -> dinv
    k_deg_init<<<nblk_N, 256, 0, stream>>>(dinv);
    k_deg_count<<<nblk_E, 256, 0, stream>>>(col, dinv);
    k_dinv<<<nblk_N, 256, 0, stream>>>(dinv);

    // layer 1: h = x @ W1 ; agg1 = A_hat h
    k_gemm<<<nblk_G, 256, 0, stream>>>(x, W1, nullptr, bufA, 0);
    k_selfinit<<<nblk_ND, 256, 0, stream>>>(bufA, dinv, bufB);
    k_scatter<<<nblk_ED, 256, 0, stream>>>(row, col, dinv, bufA, bufB);

    // layer 2: h = relu(agg1 + b1) @ W2 ; agg2
    k_gemm<<<nblk_G, 256, 0, stream>>>(bufB, W2, b1, bufA, 1);
    k_selfinit<<<nblk_ND, 256, 0, stream>>>(bufA, dinv, bufB);
    k_scatter<<<nblk_ED, 256, 0, stream>>>(row, col, dinv, bufA, bufB);

    // layer 3: h = relu(agg2 + b2) @ W3 ; agg3
    k_gemm<<<nblk_G, 256, 0, stream>>>(bufB, W3, b2, bufA, 1);
    k_selfinit<<<nblk_ND, 256, 0, stream>>>(bufA, dinv, bufB);
    k_scatter<<<nblk_ED, 256, 0, stream>>>(row, col, dinv, bufA, bufB);

    // pool: mean over graphs of relu(agg3 + b3)
    hipMemsetAsync(pool, 0, (N_GRAPHS * DF + N_GRAPHS) * sizeof(float), stream);
    k_pool<<<nblk_ND, 256, 0, stream>>>(bufB, b3, batch, pool, cnt);
    k_div<<<(N_GRAPHS * DF + 255) / 256, 256, 0, stream>>>(pool, cnt, out);
}

// Round 2
// 503.765 us; speedup vs baseline: 2.2216x; 2.2216x over previous
//
#include <hip/hip_runtime.h>

#define N_NODES   50000
#define N_EDGES   800000
#define DF        64          // feature dim (D_IN == D_HID == 64)
#define N_GRAPHS  64
#define NPAD      50176       // 196*256, padded node count for the scan

// ---------------- CSR build: count -> scan -> fill ----------------

__global__ void k_count(const int* __restrict__ col, int* __restrict__ cnt) {
    int e = blockIdx.x * blockDim.x + threadIdx.x;
    if (e < N_EDGES) atomicAdd(&cnt[col[e]], 1);
}

__global__ void k_dinv(const int* __restrict__ cnt, float* __restrict__ dinv) {
    int i = blockIdx.x * blockDim.x + threadIdx.x;
    if (i < N_NODES) dinv[i] = rsqrtf((float)(cnt[i] + 1));   // +1 self-loop
}

// per-block exclusive scan (Hillis-Steele), 196 blocks x 256
__global__ __launch_bounds__(256)
void k_scan_block(const int* __restrict__ cnt, int* __restrict__ offs,
                  int* __restrict__ bsum) {
    __shared__ int s[256];
    int t = threadIdx.x;
    int i = blockIdx.x * 256 + t;          // i < 50176 by construction
    int v = cnt[i];
    s[t] = v; __syncthreads();
    #pragma unroll
    for (int off = 1; off < 256; off <<= 1) {
        int x = (t >= off) ? s[t - off] : 0;
        __syncthreads();
        s[t] += x;
        __syncthreads();
    }
    offs[i] = s[t] - v;                    // exclusive
    if (t == 255) bsum[blockIdx.x] = s[255];
}

__global__ void k_scan_bsum(int* __restrict__ bsum) {
    if (threadIdx.x == 0 && blockIdx.x == 0) {
        int run = 0;
        for (int b = 0; b < 196; ++b) { int v = bsum[b]; bsum[b] = run; run += v; }
    }
}

__global__ void k_scan_add(int* __restrict__ offs, const int* __restrict__ bsum,
                           int* __restrict__ cursor) {
    int i = blockIdx.x * 256 + threadIdx.x;
    int v = offs[i] + bsum[blockIdx.x];
    offs[i] = v; cursor[i] = v;
}

__global__ void k_fill(const int* __restrict__ row, const int* __restrict__ col,
                       int* __restrict__ cursor, int* __restrict__ esrc) {
    int e = blockIdx.x * blockDim.x + threadIdx.x;
    if (e < N_EDGES) {
        int slot = atomicAdd(&cursor[col[e]], 1);
        esrc[slot] = row[e];
    }
}

// ---------------- GEMM: out = act(in [+ bias]) @ W ----------------
#define ROWS_PER_BLOCK 16

__global__ __launch_bounds__(256)
void k_gemm(const float* __restrict__ in, const float* __restrict__ W,
            const float* __restrict__ bias, float* __restrict__ out,
            int relu_in) {
    __shared__ float Ws[DF][DF];                  // 16 KB
    __shared__ float Xs[ROWS_PER_BLOCK][DF];      // 4 KB

    const int t = threadIdx.x;
    const int row0 = blockIdx.x * ROWS_PER_BLOCK;

    for (int i = t; i < DF * DF; i += 256)
        Ws[i >> 6][i & 63] = W[i];

    for (int i = t; i < ROWS_PER_BLOCK * DF; i += 256) {
        int r = i >> 6, k = i & 63;
        float v = in[(row0 + r) * DF + k];
        if (relu_in) { v += bias[k]; v = v > 0.0f ? v : 0.0f; }
        Xs[r][k] = v;
    }
    __syncthreads();

    const int col   = t & 63;
    const int rbase = (t >> 6) * 4;
    float a0 = 0.f, a1 = 0.f, a2 = 0.f, a3 = 0.f;
    #pragma unroll
    for (int k = 0; k < DF; ++k) {
        float w = Ws[k][col];
        a0 += Xs[rbase + 0][k] * w;
        a1 += Xs[rbase + 1][k] * w;
        a2 += Xs[rbase + 2][k] * w;
        a3 += Xs[rbase + 3][k] * w;
    }
    out[(row0 + rbase + 0) * DF + col] = a0;
    out[(row0 + rbase + 1) * DF + col] = a1;
    out[(row0 + rbase + 2) * DF + col] = a2;
    out[(row0 + rbase + 3) * DF + col] = a3;
}

// ---------------- gather aggregation: one wave per destination node ----------------
// agg[c] = dinv[c] * ( dinv[c]*h[c] + sum_{r in in(c)} dinv[r]*h[r] )
__global__ __launch_bounds__(256)
void k_gather(const int* __restrict__ offs, const int* __restrict__ esrc,
              const float* __restrict__ dinv, const float* __restrict__ h,
              float* __restrict__ agg) {
    int n = blockIdx.x * 4 + (threadIdx.x >> 6);
    int d = threadIdx.x & 63;
    if (n >= N_NODES) return;
    float dc = dinv[n];
    float acc = h[n * DF + d] * dc;           // self-loop (x dinv[c], final dc later)
    int s0 = offs[n], s1 = offs[n + 1];
    for (int s = s0; s < s1; ++s) {
        int r = esrc[s];                      // wave-uniform -> broadcast
        acc += h[r * DF + d] * dinv[r];
    }
    agg[n * DF + d] = acc * dc;
}

// ---------------- hierarchical pool (batch is sorted) ----------------
#define POOL_NPW 128   // nodes per wave

__global__ __launch_bounds__(256)
void k_pool2(const float* __restrict__ agg, const float* __restrict__ b,
             const int* __restrict__ batch, float* __restrict__ pool,
             float* __restrict__ cnt) {
    const int wave = threadIdx.x >> 6;
    const int d    = threadIdx.x & 63;
    int n0 = (blockIdx.x * 4 + wave) * POOL_NPW;
    if (n0 >= N_NODES) return;
    int n1 = n0 + POOL_NPW; if (n1 > N_NODES) n1 = N_NODES;
    float bb = b[d];
    float acc = 0.f, c = 0.f;
    int g = batch[n0];
    for (int n = n0; n < n1; ++n) {
        int bg = batch[n];                    // wave-uniform broadcast
        if (bg != g) {
            atomicAdd(&pool[g * DF + d], acc);
            if (d == 0) atomicAdd(&cnt[g], c);
            acc = 0.f; c = 0.f; g = bg;
        }
        float v = agg[n * DF + d] + bb;
        acc += v > 0.f ? v : 0.f;
        c += 1.f;
    }
    atomicAdd(&pool[g * DF + d], acc);
    if (d == 0) atomicAdd(&cnt[g], c);
}

__global__ void k_div(const float* __restrict__ pool, const float* __restrict__ cnt,
                      float* __restrict__ out) {
    int idx = blockIdx.x * blockDim.x + threadIdx.x;
    if (idx < N_GRAPHS * DF) {
        float c = cnt[idx >> 6];
        out[idx] = pool[idx] / fmaxf(c, 1.0f);
    }
}

// ---------------- launch ----------------

extern "C" void kernel_launch(void* const* d_in, const int* in_sizes, int n_in,
                              void* d_out, int out_size, void* d_ws, size_t ws_size,
                              hipStream_t stream) {
    const float* x     = (const float*)d_in[0];
    const int*   ei    = (const int*)d_in[1];      // [2, E] flat: row then col
    const int*   batch = (const int*)d_in[2];
    const float* W1    = (const float*)d_in[3];
    const float* b1    = (const float*)d_in[4];
    const float* W2    = (const float*)d_in[5];
    const float* b2    = (const float*)d_in[6];
    const float* W3    = (const float*)d_in[7];
    const float* b3    = (const float*)d_in[8];
    float* out = (float*)d_out;

    const int* row = ei;             // source
    const int* col = ei + N_EDGES;   // target (aggregation index)

    // workspace layout (4-byte elements)
    char* wsb = (char*)d_ws;
    int*   cnti   = (int*)wsb;                       // NPAD
    int*   offs   = cnti + NPAD;                     // NPAD (need offs[50000])
    int*   cursor = offs + NPAD;                     // NPAD
    int*   bsum   = cursor + NPAD;                   // 256
    int*   esrc   = bsum + 256;                      // N_EDGES
    float* dinv   = (float*)(esrc + N_EDGES);        // NPAD
    float* bufA   = dinv + NPAD;                     // N_NODES*DF
    float* bufB   = bufA + N_NODES * DF;             // N_NODES*DF
    float* pool   = bufB + N_NODES * DF;             // N_GRAPHS*DF
    float* cnt    = pool + N_GRAPHS * DF;            // N_GRAPHS

    const int nblk_E  = (N_EDGES + 255) / 256;       // 3125
    const int nblk_N  = (N_NODES + 255) / 256;       // 196
    const int nblk_G  = 3125;                        // 50000/16 gemm blocks
    const int nblk_GA = (N_NODES + 3) / 4;           // gather: 1 wave/node
    const int nblk_P  = (N_NODES + 4 * POOL_NPW - 1) / (4 * POOL_NPW); // 98

    // CSR build + dinv
    hipMemsetAsync(cnti, 0, NPAD * sizeof(int), stream);
    k_count<<<nblk_E, 256, 0, stream>>>(col, cnti);
    k_dinv<<<nblk_N, 256, 0, stream>>>(cnti, dinv);
    k_scan_block<<<196, 256, 0, stream>>>(cnti, offs, bsum);
    k_scan_bsum<<<1, 64, 0, stream>>>(bsum);
    k_scan_add<<<196, 256, 0, stream>>>(offs, bsum, cursor);
    k_fill<<<nblk_E, 256, 0, stream>>>(row, col, cursor, esrc);

    // layer 1
    k_gemm<<<nblk_G, 256, 0, stream>>>(x, W1, nullptr, bufA, 0);
    k_gather<<<nblk_GA, 256, 0, stream>>>(offs, esrc, dinv, bufA, bufB);
    // layer 2
    k_gemm<<<nblk_G, 256, 0, stream>>>(bufB, W2, b1, bufA, 1);
    k_gather<<<nblk_GA, 256, 0, stream>>>(offs, esrc, dinv, bufA, bufB);
    // layer 3
    k_gemm<<<nblk_G, 256, 0, stream>>>(bufB, W3, b2, bufA, 1);
    k_gather<<<nblk_GA, 256, 0, stream>>>(offs, esrc, dinv, bufA, bufB);

    // mean pool
    hipMemsetAsync(pool, 0, (N_GRAPHS * DF + N_GRAPHS) * sizeof(float), stream);
    k_pool2<<<nblk_P, 256, 0, stream>>>(bufB, b3, batch, pool, cnt);
    k_div<<<(N_GRAPHS * DF + 255) / 256, 256, 0, stream>>>(pool, cnt, out);
}

// Round 3
// 417.635 us; speedup vs baseline: 2.6797x; 1.2062x over previous
//
#include <hip/hip_runtime.h>

#define N_NODES   50000
#define N_EDGES   800000
#define DF        64          // feature dim (D_IN == D_HID == 64)
#define N_GRAPHS  64
#define NPAD      50176       // 196*256, padded node count for the scan

// ---------------- CSR build: count -> scan -> fill ----------------

__global__ void k_count(const int* __restrict__ col, int* __restrict__ cnt) {
    int e = blockIdx.x * blockDim.x + threadIdx.x;
    if (e < N_EDGES) atomicAdd(&cnt[col[e]], 1);
}

__global__ void k_dinv(const int* __restrict__ cnt, float* __restrict__ dinv) {
    int i = blockIdx.x * blockDim.x + threadIdx.x;
    if (i < N_NODES) dinv[i] = rsqrtf((float)(cnt[i] + 1));   // +1 self-loop
}

// per-block exclusive scan (Hillis-Steele), 196 blocks x 256
__global__ __launch_bounds__(256)
void k_scan_block(const int* __restrict__ cnt, int* __restrict__ offs,
                  int* __restrict__ bsum) {
    __shared__ int s[256];
    int t = threadIdx.x;
    int i = blockIdx.x * 256 + t;
    int v = cnt[i];
    s[t] = v; __syncthreads();
    #pragma unroll
    for (int off = 1; off < 256; off <<= 1) {
        int x = (t >= off) ? s[t - off] : 0;
        __syncthreads();
        s[t] += x;
        __syncthreads();
    }
    offs[i] = s[t] - v;                    // exclusive
    if (t == 255) bsum[blockIdx.x] = s[255];
}

__global__ void k_scan_bsum(int* __restrict__ bsum) {
    if (threadIdx.x == 0 && blockIdx.x == 0) {
        int run = 0;
        for (int b = 0; b < 196; ++b) { int v = bsum[b]; bsum[b] = run; run += v; }
    }
}

__global__ void k_scan_add(int* __restrict__ offs, const int* __restrict__ bsum,
                           int* __restrict__ cursor) {
    int i = blockIdx.x * 256 + threadIdx.x;
    int v = offs[i] + bsum[blockIdx.x];
    offs[i] = v; cursor[i] = v;
}

__global__ void k_fill(const int* __restrict__ row, const int* __restrict__ col,
                       int* __restrict__ cursor, int* __restrict__ esrc) {
    int e = blockIdx.x * blockDim.x + threadIdx.x;
    if (e < N_EDGES) {
        int slot = atomicAdd(&cursor[col[e]], 1);
        esrc[slot] = row[e];
    }
}

// ---------------- GEMM: out = act(in [+ bias]) @ W ----------------
// 64x64 block tile, 256 threads, 4x4 register tile per thread.
// X staged TRANSPOSED (XsT[k][r], ldx=68 -> float4-aligned, conflict-light)
#define GB_ROWS 64
#define LDX 68

__global__ __launch_bounds__(256)
void k_gemm(const float* __restrict__ in, const float* __restrict__ W,
            const float* __restrict__ bias, float* __restrict__ out,
            int relu_in) {
    __shared__ float XsT[DF][LDX];   // 17 KB
    __shared__ float Ws[DF][DF];     // 16 KB

    const int t = threadIdx.x;
    const int row0 = blockIdx.x * GB_ROWS;

    // stage W (4096 floats, float4 coalesced)
    for (int idx = t * 4; idx < DF * DF; idx += 256 * 4) {
        float4 w = *(const float4*)&W[idx];
        Ws[idx >> 6][idx & 63] = w.x;
        Ws[idx >> 6][(idx & 63) + 1] = w.y;
        Ws[idx >> 6][(idx & 63) + 2] = w.z;
        Ws[idx >> 6][(idx & 63) + 3] = w.w;
    }

    // stage X transposed, fusing previous layer's bias + ReLU
    // thread t: row r = t>>2, k-chunk k0 = (t&3)*16, 4x float4
    {
        const int r  = t >> 2;
        const int k0 = (t & 3) * 16;
        const int gr = row0 + r;
        const bool valid = gr < N_NODES;
        #pragma unroll
        for (int kk = 0; kk < 16; kk += 4) {
            float4 v = valid ? *(const float4*)&in[gr * DF + k0 + kk]
                             : make_float4(0.f, 0.f, 0.f, 0.f);
            if (relu_in) {
                v.x += bias[k0 + kk + 0]; v.x = v.x > 0.f ? v.x : 0.f;
                v.y += bias[k0 + kk + 1]; v.y = v.y > 0.f ? v.y : 0.f;
                v.z += bias[k0 + kk + 2]; v.z = v.z > 0.f ? v.z : 0.f;
                v.w += bias[k0 + kk + 3]; v.w = v.w > 0.f ? v.w : 0.f;
            }
            XsT[k0 + kk + 0][r] = v.x;
            XsT[k0 + kk + 1][r] = v.y;
            XsT[k0 + kk + 2][r] = v.z;
            XsT[k0 + kk + 3][r] = v.w;
        }
    }
    __syncthreads();

    const int i = (t & 15) * 4;   // row offset in tile
    const int j = (t >> 4) * 4;   // col offset
    float acc[4][4] = {};
    #pragma unroll
    for (int k = 0; k < DF; ++k) {
        float4 xv = *(const float4*)&XsT[k][i];
        float4 wv = *(const float4*)&Ws[k][j];
        acc[0][0] += xv.x * wv.x; acc[0][1] += xv.x * wv.y;
        acc[0][2] += xv.x * wv.z; acc[0][3] += xv.x * wv.w;
        acc[1][0] += xv.y * wv.x; acc[1][1] += xv.y * wv.y;
        acc[1][2] += xv.y * wv.z; acc[1][3] += xv.y * wv.w;
        acc[2][0] += xv.z * wv.x; acc[2][1] += xv.z * wv.y;
        acc[2][2] += xv.z * wv.z; acc[2][3] += xv.z * wv.w;
        acc[3][0] += xv.w * wv.x; acc[3][1] += xv.w * wv.y;
        acc[3][2] += xv.w * wv.z; acc[3][3] += xv.w * wv.w;
    }
    #pragma unroll
    for (int u = 0; u < 4; ++u) {
        int gr = row0 + i + u;
        if (gr < N_NODES)
            *(float4*)&out[gr * DF + j] =
                make_float4(acc[u][0], acc[u][1], acc[u][2], acc[u][3]);
    }
}

// ---------------- gather aggregation: one wave per destination node ----------------
// agg[c] = dinv[c] * ( dinv[c]*h[c] + sum_{r in in(c)} dinv[r]*h[r] )
// edge loop unrolled x4 for memory-level parallelism
__global__ __launch_bounds__(256)
void k_gather(const int* __restrict__ offs, const int* __restrict__ esrc,
              const float* __restrict__ dinv, const float* __restrict__ h,
              float* __restrict__ agg) {
    int n = blockIdx.x * 4 + (threadIdx.x >> 6);
    int d = threadIdx.x & 63;
    if (n >= N_NODES) return;
    float dc = dinv[n];
    float acc = h[n * DF + d] * dc;           // self-loop
    int s0 = offs[n], s1 = offs[n + 1];
    int s = s0;
    for (; s + 4 <= s1; s += 4) {
        int r0 = esrc[s + 0], r1 = esrc[s + 1];
        int r2 = esrc[s + 2], r3 = esrc[s + 3];
        float w0 = dinv[r0], w1 = dinv[r1], w2 = dinv[r2], w3 = dinv[r3];
        float v0 = h[r0 * DF + d], v1 = h[r1 * DF + d];
        float v2 = h[r2 * DF + d], v3 = h[r3 * DF + d];
        acc += v0 * w0; acc += v1 * w1; acc += v2 * w2; acc += v3 * w3;
    }
    for (; s < s1; ++s) {
        int r = esrc[s];
        acc += h[r * DF + d] * dinv[r];
    }
    agg[n * DF + d] = acc * dc;
}

// ---------------- hierarchical pool (batch is sorted) ----------------
#define POOL_NPW 128   // nodes per wave

__global__ __launch_bounds__(256)
void k_pool2(const float* __restrict__ agg, const float* __restrict__ b,
             const int* __restrict__ batch, float* __restrict__ pool,
             float* __restrict__ cnt) {
    const int wave = threadIdx.x >> 6;
    const int d    = threadIdx.x & 63;
    int n0 = (blockIdx.x * 4 + wave) * POOL_NPW;
    if (n0 >= N_NODES) return;
    int n1 = n0 + POOL_NPW; if (n1 > N_NODES) n1 = N_NODES;
    float bb = b[d];
    float acc = 0.f, c = 0.f;
    int g = batch[n0];
    for (int n = n0; n < n1; ++n) {
        int bg = batch[n];
        if (bg != g) {
            atomicAdd(&pool[g * DF + d], acc);
            if (d == 0) atomicAdd(&cnt[g], c);
            acc = 0.f; c = 0.f; g = bg;
        }
        float v = agg[n * DF + d] + bb;
        acc += v > 0.f ? v : 0.f;
        c += 1.f;
    }
    atomicAdd(&pool[g * DF + d], acc);
    if (d == 0) atomicAdd(&cnt[g], c);
}

__global__ void k_div(const float* __restrict__ pool, const float* __restrict__ cnt,
                      float* __restrict__ out) {
    int idx = blockIdx.x * blockDim.x + threadIdx.x;
    if (idx < N_GRAPHS * DF) {
        float c = cnt[idx >> 6];
        out[idx] = pool[idx] / fmaxf(c, 1.0f);
    }
}

// ---------------- launch ----------------

extern "C" void kernel_launch(void* const* d_in, const int* in_sizes, int n_in,
                              void* d_out, int out_size, void* d_ws, size_t ws_size,
                              hipStream_t stream) {
    const float* x     = (const float*)d_in[0];
    const int*   ei    = (const int*)d_in[1];      // [2, E] flat: row then col
    const int*   batch = (const int*)d_in[2];
    const float* W1    = (const float*)d_in[3];
    const float* b1    = (const float*)d_in[4];
    const float* W2    = (const float*)d_in[5];
    const float* b2    = (const float*)d_in[6];
    const float* W3    = (const float*)d_in[7];
    const float* b3    = (const float*)d_in[8];
    float* out = (float*)d_out;

    const int* row = ei;             // source
    const int* col = ei + N_EDGES;   // target (aggregation index)

    // workspace layout (4-byte elements)
    char* wsb = (char*)d_ws;
    int*   cnti   = (int*)wsb;                       // NPAD
    int*   offs   = cnti + NPAD;                     // NPAD
    int*   cursor = offs + NPAD;                     // NPAD
    int*   bsum   = cursor + NPAD;                   // 256
    int*   esrc   = bsum + 256;                      // N_EDGES
    float* dinv   = (float*)(esrc + N_EDGES);        // NPAD
    float* bufA   = dinv + NPAD;                     // N_NODES*DF
    float* bufB   = bufA + N_NODES * DF;             // N_NODES*DF
    float* pool   = bufB + N_NODES * DF;             // N_GRAPHS*DF
    float* cnt    = pool + N_GRAPHS * DF;            // N_GRAPHS

    const int nblk_E  = (N_EDGES + 255) / 256;       // 3125
    const int nblk_N  = (N_NODES + 255) / 256;       // 196
    const int nblk_G  = (N_NODES + GB_ROWS - 1) / GB_ROWS;   // 782
    const int nblk_GA = (N_NODES + 3) / 4;           // gather: 1 wave/node
    const int nblk_P  = (N_NODES + 4 * POOL_NPW - 1) / (4 * POOL_NPW); // 98

    // CSR build + dinv
    hipMemsetAsync(cnti, 0, NPAD * sizeof(int), stream);
    k_count<<<nblk_E, 256, 0, stream>>>(col, cnti);
    k_dinv<<<nblk_N, 256, 0, stream>>>(cnti, dinv);
    k_scan_block<<<196, 256, 0, stream>>>(cnti, offs, bsum);
    k_scan_bsum<<<1, 64, 0, stream>>>(bsum);
    k_scan_add<<<196, 256, 0, stream>>>(offs, bsum, cursor);
    k_fill<<<nblk_E, 256, 0, stream>>>(row, col, cursor, esrc);

    // layer 1
    k_gemm<<<nblk_G, 256, 0, stream>>>(x, W1, nullptr, bufA, 0);
    k_gather<<<nblk_GA, 256, 0, stream>>>(offs, esrc, dinv, bufA, bufB);
    // layer 2
    k_gemm<<<nblk_G, 256, 0, stream>>>(bufB, W2, b1, bufA, 1);
    k_gather<<<nblk_GA, 256, 0, stream>>>(offs, esrc, dinv, bufA, bufB);
    // layer 3
    k_gemm<<<nblk_G, 256, 0, stream>>>(bufB, W3, b2, bufA, 1);
    k_gather<<<nblk_GA, 256, 0, stream>>>(offs, esrc, dinv, bufA, bufB);

    // mean pool
    hipMemsetAsync(pool, 0, (N_GRAPHS * DF + N_GRAPHS) * sizeof(float), stream);
    k_pool2<<<nblk_P, 256, 0, stream>>>(bufB, b3, batch, pool, cnt);
    k_div<<<(N_GRAPHS * DF + 255) / 256, 256, 0, stream>>>(pool, cnt, out);
}